// Round 9
// baseline (259.850 us; speedup 1.0000x reference)
//
#include <hip/hip_runtime.h>

#define N_NODES 50000
#define N_EDGES 800000
#define D 128
#define CAP 48                        // max in-degree slots (verified sufficient R2-R8)

#define FILLB (N_EDGES / 256)         // 3125 fill blocks (exact), one edge per thread
#define PACKB 24                      // W-pack blocks (96 wids)

// ---- src-side binning for odeg (replay-safe: histogram is order-independent) ----
#define ABLK 400                      // binning blocks
#define AEDGES (N_EDGES / ABLK)       // 2000 edges per binning block (exact)
#define BW 512                        // bucket width (nodes); bucket = src>>9
#define NBUCK 98                      // ceil(50176/512)
#define BCAP 10240                    // per-bucket capacity (mean 8163, +23 sigma)

// ---- degree-class permutation (deterministic counting sort, replay-safe) ----
#define PERMB 196                     // ceil(50000/256) perm blocks
#define HCONVB 6251                   // hconv main blocks: ceil((N_NODES*32+64)/256)

typedef __attribute__((ext_vector_type(4))) float f32x4;
typedef __attribute__((ext_vector_type(8))) short s16x8;

__device__ inline unsigned short f32_to_bf16_rtne(float f) {
    union { float f; unsigned u; } c; c.f = f;
    unsigned u = c.u;
    u += 0x7FFF + ((u >> 16) & 1);
    return (unsigned short)(u >> 16);
}
__device__ inline float bf16_to_f32(unsigned short h) {
    union { unsigned u; float f; } c; c.u = ((unsigned)h) << 16;
    return c.f;
}
__device__ inline unsigned pack_bf2(float a, float b) {
    return (unsigned)f32_to_bf16_rtne(a) | ((unsigned)f32_to_bf16_rtne(b) << 16);
}
__device__ inline void unpack_bf2(unsigned u, float& a, float& b) {
    union { unsigned u; float f; } c0, c1;
    c0.u = u << 16; c1.u = u & 0xFFFF0000u;
    a = c0.f; b = c1.f;
}
__device__ inline void acc_uint4(uint4 v, float* a) {
    float f0, f1;
    unpack_bf2(v.x, f0, f1); a[0] += f0; a[1] += f1;
    unpack_bf2(v.y, f0, f1); a[2] += f0; a[3] += f1;
    unpack_bf2(v.z, f0, f1); a[4] += f0; a[5] += f1;
    unpack_bf2(v.w, f0, f1); a[6] += f0; a[7] += f1;
}

// ---------------- build: slot fill (frozen ordering) | W-pack | src binning ----------------
// Scattered-op model (R0-R7, quantitative): ~40ns + ~30B writeback per scattered sub-line
// global op, any type. Fill = 2 ops/edge = ~52-57us floor. Slot ORDERING frozen (R4).

__global__ __launch_bounds__(256) void build_fill(const int* __restrict__ src,
                                                  const int* __restrict__ dst,
                                                  int* __restrict__ cursor,
                                                  int* __restrict__ gcurS,
                                                  unsigned short* __restrict__ sbin,
                                                  unsigned short* __restrict__ slots,
                                                  const float* __restrict__ W0,
                                                  const float* __restrict__ W1,
                                                  const float* __restrict__ W2,
                                                  s16x8* __restrict__ wpk) {
    int b = blockIdx.x;
    if (b < FILLB) {
        int e = b * 256 + threadIdx.x;
        int s = src[e];
        int d = dst[e];
        int pos = atomicAdd(&cursor[d], 1);
        if (pos < CAP) slots[d * CAP + pos] = (unsigned short)s;
    } else if (b < FILLB + PACKB) {
        // ---- W-pack role ----
        int wid = (b - FILLB) * 4 + (threadIdx.x >> 6);   // 0..95 = layer(3) x ct(8) x ks(4)
        if (wid >= 96) return;
        int lane = threadIdx.x & 63;
        int layer = wid / 32, rem = wid % 32;
        int ct = rem >> 2, ks = rem & 3;
        const float* W = (layer == 0) ? W0 : (layer == 1) ? W1 : W2;
        int col = ct * 16 + (lane & 15);
        int k0  = ks * 32 + (lane >> 4) * 8;
        s16x8 hi, lo;
#pragma unroll
        for (int j = 0; j < 8; j++) {
            float w = W[(k0 + j) * D + col];
            unsigned short h = f32_to_bf16_rtne(w);
            hi[j] = (short)h;
            lo[j] = (short)f32_to_bf16_rtne(w - bf16_to_f32(h));
        }
        int idx = layer * 4096 + (ct * 4 + ks) * 64 + lane;
        wpk[idx]        = hi;
        wpk[idx + 2048] = lo;
    } else {
        // ---- src binning role (odeg precursor) ----
        int bb = b - FILLB - PACKB;                       // 0..399
        __shared__ int cntS[NBUCK], baseS[NBUCK], c2S[NBUCK];
        for (int i = threadIdx.x; i < NBUCK; i += 256) { cntS[i] = 0; c2S[i] = 0; }
        __syncthreads();
        int e0 = bb * AEDGES;
        for (int i = threadIdx.x; i < AEDGES; i += 256)
            atomicAdd(&cntS[src[e0 + i] >> 9], 1);
        __syncthreads();
        for (int i = threadIdx.x; i < NBUCK; i += 256)
            baseS[i] = atomicAdd(&gcurS[i], cntS[i]);
        __syncthreads();
        for (int i = threadIdx.x; i < AEDGES; i += 256) {
            int s = src[e0 + i];
            int bs = s >> 9;
            int rs = atomicAdd(&c2S[bs], 1);
            int os = baseS[bs] + rs;
            if (os < BCAP) sbin[bs * BCAP + os] = (unsigned short)s;
        }
    }
}

// ---------------- odeg hist (b<98) | perm_count: degree-class histogram per 256-node block ----------------
// Degree-class sort (R9): class = ceil(min(indeg,CAP)/8) in 0..6. Counting sort stable by
// node id -> FULLY deterministic permutation (replay-safe). Per-node math in fused_layer
// is bit-identical; only node->block mapping changes, removing round-count divergence
// (block time ~ max over 16 random Poisson(16) degrees -> uniform per block).

__global__ __launch_bounds__(512) void odeg_hist(const unsigned short* __restrict__ sbin,
                                                 const int* __restrict__ gcurS,
                                                 int* __restrict__ odeg,
                                                 const int* __restrict__ indeg,
                                                 int* __restrict__ pcnt) {
    int b = blockIdx.x;
    if (b < NBUCK) {
        __shared__ int cnt[BW];
        for (int i = threadIdx.x; i < BW; i += 512) cnt[i] = 0;
        __syncthreads();
        int nE = min(gcurS[b], BCAP);
        const unsigned short* es = sbin + (size_t)b * BCAP;
        for (int i = threadIdx.x; i < nE; i += 512)
            atomicAdd(&cnt[es[i] & (BW - 1)], 1);
        __syncthreads();
        int n0 = b * BW;
        for (int i = threadIdx.x; i < BW; i += 512)
            if (n0 + i < N_NODES) odeg[n0 + i] = cnt[i];
    } else {
        int b2 = b - NBUCK;                   // 0..195
        __shared__ int h8[8];
        if (threadIdx.x < 8) h8[threadIdx.x] = 0;
        __syncthreads();
        if (threadIdx.x < 256) {
            int n = b2 * 256 + threadIdx.x;
            if (n < N_NODES) {
                int c = (min(indeg[n], CAP) + 7) >> 3;   // 0..6
                atomicAdd(&h8[c], 1);
            }
        }
        __syncthreads();
        if (threadIdx.x < 8) pcnt[b2 * 8 + threadIdx.x] = h8[threadIdx.x];
    }
}

// ---------------- perm_scan: exclusive scans (serial per class -> deterministic) ----------------
// Classes placed DESCENDING (high-degree blocks scheduled first -> fast blocks fill the tail).

__global__ __launch_bounds__(256) void perm_scan(int* __restrict__ pcnt,
                                                 int* __restrict__ cbase) {
    __shared__ int tot[8];
    int t = threadIdx.x;
    if (t < 8) {
        int run = 0;
        for (int b = 0; b < PERMB; b++) {
            int v = pcnt[b * 8 + t];
            pcnt[b * 8 + t] = run;
            run += v;
        }
        tot[t] = run;
    }
    __syncthreads();
    if (t == 0) {
        int run = 0;
        for (int c = 7; c >= 0; c--) { cbase[c] = run; run += tot[c]; }
    }
}

// ---------------- hconv (main) | perm_place (stable intra-block ranks via ballots) ----------------

__global__ __launch_bounds__(256) void hconv(const float4* __restrict__ h,
                                             const int* __restrict__ odeg,
                                             const int* __restrict__ indeg,
                                             const int* __restrict__ pcnt,
                                             const int* __restrict__ cbase,
                                             unsigned short* __restrict__ perm,
                                             float* __restrict__ s_out,
                                             uint2* __restrict__ hbA,
                                             uint2* __restrict__ hbB) {
    if (blockIdx.x < HCONVB) {
        int gid = blockIdx.x * 256 + threadIdx.x;   // one float4 (4 channels) per thread
        const int total = N_NODES * 32;
        if (gid < total) {
            int node = gid >> 5;
            float so = rsqrtf(fmaxf((float)odeg[node], 1.0f));
            if ((gid & 31) == 0) s_out[node] = so;   // persist for fused_layer epilogue
            float4 v = h[gid];
            hbA[gid] = make_uint2(pack_bf2(so * v.x, so * v.y), pack_bf2(so * v.z, so * v.w));
        } else if (gid < total + 32) {
            hbA[total + (gid - total)] = make_uint2(0u, 0u);        // zero row of actA
        } else if (gid < total + 64) {
            hbB[total + (gid - total - 32)] = make_uint2(0u, 0u);   // zero row of actB
        }
    } else {
        int b2 = blockIdx.x - HCONVB;               // 0..195
        int t = threadIdx.x, lane = t & 63, wv2 = t >> 6;
        __shared__ int whist[4][8];
        int n = b2 * 256 + t;
        int c = 7;
        if (n < N_NODES) c = (min(indeg[n], CAP) + 7) >> 3;
        int rank_in_wave = 0;
        for (int k = 0; k < 8; k++) {
            unsigned long long m = __ballot(c == k);
            if (c == k) rank_in_wave = (int)__popcll(m & ((1ull << lane) - 1ull));
            if (lane == 0) whist[wv2][k] = (int)__popcll(m);
        }
        __syncthreads();
        if (n < N_NODES) {
            int before = 0;
            for (int w2 = 0; w2 < wv2; w2++) before += whist[w2][c];
            int pos = cbase[c] + pcnt[b2 * 8 + c] + before + rank_in_wave;
            perm[pos] = (unsigned short)n;
        }
    }
}

// ---------------- fused layer: gather-aggregate -> LDS(split-bf16) -> MFMA GEMM ----------------
// R8 pipeline reverted (regressed: not per-wave-MLP-bound). R9: node order = perm
// (degree-class sorted) -> uniform round count per block, ~25% fewer issued gathers.
// Per-node arithmetic bit-identical to R7; output written through perm.

__global__ __launch_bounds__(256) void fused_layer(const uint4* __restrict__ x,
                                                   const unsigned short* __restrict__ slots,
                                                   const int* __restrict__ deg,
                                                   const unsigned short* __restrict__ perm,
                                                   const s16x8* __restrict__ wpk,
                                                   const float* __restrict__ bias,
                                                   const float* __restrict__ s_out,
                                                   float* __restrict__ outf,
                                                   unsigned short* __restrict__ outb) {
    __shared__ s16x8 mHI[16 * 17];
    __shared__ s16x8 mLO[16 * 17];
    int tid = threadIdx.x;
    int row0 = blockIdx.x * 16;

    // ---- phase 1: aggregate ----
    {
        int nloc = tid >> 4;          // local node 0..15
        int l    = tid & 15;          // chunk: channels l*8 .. l*8+7
        int node = (int)perm[row0 + nloc];
        int dgraw = deg[node];
        int dg = min(dgraw, CAP);
        int base = node * CAP;
        // prefetch all slot indices; OOB -> zero row
        int idx0 = (l      < dg) ? (int)slots[base + l]      : N_NODES;
        int idx1 = (16 + l < dg) ? (int)slots[base + 16 + l] : N_NODES;
        int idx2 = (32 + l < dg) ? (int)slots[base + 32 + l] : N_NODES;

        float a[8];
#pragma unroll
        for (int j = 0; j < 8; j++) a[j] = 0.f;

        int nr = (dg + 7) >> 3;       // rounds of 8 (0..6), no tails
        for (int r = 0; r < nr; r++) {
            int c = r >> 1;
            int v = (c == 0) ? idx0 : ((c == 1) ? idx1 : idx2);
            int k = (r & 1) * 8;
            int s0 = __shfl(v, k + 0, 16), s1 = __shfl(v, k + 1, 16);
            int s2 = __shfl(v, k + 2, 16), s3 = __shfl(v, k + 3, 16);
            int s4 = __shfl(v, k + 4, 16), s5 = __shfl(v, k + 5, 16);
            int s6 = __shfl(v, k + 6, 16), s7 = __shfl(v, k + 7, 16);
            uint4 g0 = x[s0 * 16 + l];
            uint4 g1 = x[s1 * 16 + l];
            uint4 g2 = x[s2 * 16 + l];
            uint4 g3 = x[s3 * 16 + l];
            uint4 g4 = x[s4 * 16 + l];
            uint4 g5 = x[s5 * 16 + l];
            uint4 g6 = x[s6 * 16 + l];
            uint4 g7 = x[s7 * 16 + l];
            acc_uint4(g0, a); acc_uint4(g1, a); acc_uint4(g2, a); acc_uint4(g3, a);
            acc_uint4(g4, a); acc_uint4(g5, a); acc_uint4(g6, a); acc_uint4(g7, a);
        }
        float si = rsqrtf(fmaxf((float)dgraw, 1.0f));
        s16x8 ahi, alo;
#pragma unroll
        for (int j = 0; j < 8; j++) {
            float av = a[j] * si;
            unsigned short hh = f32_to_bf16_rtne(av);
            ahi[j] = (short)hh;
            alo[j] = (short)f32_to_bf16_rtne(av - bf16_to_f32(hh));
        }
        mHI[nloc * 17 + l] = ahi;
        mLO[nloc * 17 + l] = alo;
    }
    __syncthreads();

    // ---- phase 2: GEMM ----
    int wv = tid >> 6;                 // wave 0..3 -> col-tiles {2wv, 2wv+1}
    int lane = tid & 63;
    int arow = lane & 15, aq = lane >> 4;
    int ct0 = wv * 2, ct1 = ct0 + 1;
    f32x4 acc0 = (f32x4)0.f, acc1 = (f32x4)0.f;

#pragma unroll
    for (int ks = 0; ks < 4; ks++) {
        s16x8 ahi = mHI[arow * 17 + ks * 4 + aq];
        s16x8 alo = mLO[arow * 17 + ks * 4 + aq];
        int idx0 = (ct0 * 4 + ks) * 64 + lane;
        int idx1 = (ct1 * 4 + ks) * 64 + lane;
        s16x8 b0h = wpk[idx0], b0l = wpk[idx0 + 2048];
        s16x8 b1h = wpk[idx1], b1l = wpk[idx1 + 2048];
        acc0 = __builtin_amdgcn_mfma_f32_16x16x32_bf16(ahi, b0h, acc0, 0, 0, 0);
        acc0 = __builtin_amdgcn_mfma_f32_16x16x32_bf16(alo, b0h, acc0, 0, 0, 0);
        acc0 = __builtin_amdgcn_mfma_f32_16x16x32_bf16(ahi, b0l, acc0, 0, 0, 0);
        acc1 = __builtin_amdgcn_mfma_f32_16x16x32_bf16(ahi, b1h, acc1, 0, 0, 0);
        acc1 = __builtin_amdgcn_mfma_f32_16x16x32_bf16(alo, b1h, acc1, 0, 0, 0);
        acc1 = __builtin_amdgcn_mfma_f32_16x16x32_bf16(ahi, b1l, acc1, 0, 0, 0);
    }

    // C/D: col = lane&15, row = (lane>>4)*4 + reg ; rows mapped through perm
    int crow0 = aq * 4;
    int colA = ct0 * 16 + arow, colB = ct1 * 16 + arow;
    float bA = bias[colA], bB = bias[colB];
#pragma unroll
    for (int r = 0; r < 4; r++) {
        int noder = (int)perm[row0 + crow0 + r];
        size_t rowoff = (size_t)noder * D;
        float vA = fmaxf(acc0[r] + bA, 0.f);
        float vB = fmaxf(acc1[r] + bB, 0.f);
        if (outf) { outf[rowoff + colA] = vA; outf[rowoff + colB] = vB; }
        if (outb) {
            float so = s_out[noder];
            outb[rowoff + colA] = f32_to_bf16_rtne(so * vA);
            outb[rowoff + colB] = f32_to_bf16_rtne(so * vB);
        }
    }
}

// ---------------- launch ----------------

extern "C" void kernel_launch(void* const* d_in, const int* in_sizes, int n_in,
                              void* d_out, int out_size, void* d_ws, size_t ws_size,
                              hipStream_t stream) {
    const float* h  = (const float*)d_in[0];
    const int*  src = (const int*)d_in[1];
    const int*  dst = (const int*)d_in[2];
    const float* W0 = (const float*)d_in[3];
    const float* b0 = (const float*)d_in[4];
    const float* W1 = (const float*)d_in[5];
    const float* b1 = (const float*)d_in[6];
    const float* W2 = (const float*)d_in[7];
    const float* b2 = (const float*)d_in[8];
    float* out = (float*)d_out;

    char* w = (char*)d_ws;
    auto carve = [&](size_t bytes) -> void* {
        void* p = (void*)w;
        w += (bytes + 255) & ~(size_t)255;
        return p;
    };
    int*      cursor  = (int*)carve((N_NODES + 128) * sizeof(int)); // cursor(indeg) + gcurS
    int*      gcurS   = cursor + N_NODES;
    int*      odeg    = (int*)carve(N_NODES * sizeof(int));         // fully written by odeg_hist
    float*    s_out   = (float*)carve(N_NODES * sizeof(float));
    int*      pcnt    = (int*)carve(PERMB * 8 * sizeof(int));       // perm block-class counts
    int*      cbase   = (int*)carve(8 * sizeof(int));
    unsigned short* perm  = (unsigned short*)carve(N_NODES * sizeof(unsigned short)); // 100 KB
    unsigned short* slots = (unsigned short*)carve((size_t)N_NODES * CAP * sizeof(unsigned short)); // 4.8 MB
    unsigned short* sbin  = (unsigned short*)carve((size_t)NBUCK * BCAP * sizeof(unsigned short));  // 2.0 MB
    unsigned short* actA  = (unsigned short*)carve((size_t)(N_NODES + 1) * D * 2);  // 12.8 MB (+zero row)
    unsigned short* actB  = (unsigned short*)carve((size_t)(N_NODES + 1) * D * 2);  // 12.8 MB
    s16x8*    wpk     = (s16x8*)carve(3 * 4096 * sizeof(s16x8));                    // 192 KB

    hipMemsetAsync(cursor, 0, (N_NODES + 128) * sizeof(int), stream);  // cursor + gcurS
    build_fill<<<FILLB + PACKB + ABLK, 256, 0, stream>>>(src, dst, cursor, gcurS, sbin, slots,
                                                         W0, W1, W2, wpk);
    odeg_hist<<<NBUCK + PERMB, 512, 0, stream>>>(sbin, gcurS, odeg, cursor, pcnt);
    perm_scan<<<1, 256, 0, stream>>>(pcnt, cbase);
    hconv<<<HCONVB + PERMB, 256, 0, stream>>>((const float4*)h, odeg, cursor, pcnt, cbase,
                                              perm, s_out, (uint2*)actA, (uint2*)actB);

    const int GRID = N_NODES / 16;   // 3125 exact

    // layer 1: actA(bf16, s_out-scaled h) -> actB
    fused_layer<<<GRID, 256, 0, stream>>>((const uint4*)actA, slots, cursor, perm,
                                          wpk, b0, s_out, nullptr, actB);
    // layer 2: actB -> actA
    fused_layer<<<GRID, 256, 0, stream>>>((const uint4*)actB, slots, cursor, perm,
                                          wpk + 4096, b1, s_out, nullptr, actA);
    // layer 3: actA -> d_out (fp32)
    fused_layer<<<GRID, 256, 0, stream>>>((const uint4*)actA, slots, cursor, perm,
                                          wpk + 8192, b2, s_out, out, nullptr);
}

// Round 10
// 253.487 us; speedup vs baseline: 1.0251x; 1.0251x over previous
//
#include <hip/hip_runtime.h>

#define N_NODES 50000
#define N_EDGES 800000
#define D 128
#define CAP 48                        // max in-degree slots (verified sufficient R2-R8)
#define NPADN 50176                   // padded node count (196*256)

#define PACKB 24                      // W-pack blocks (96 wids)

// ---- deterministic counting-sort build ----
#define ABLK 400                      // edge blocks (count & place)
#define AEDGES (N_EDGES / ABLK)       // 2000 edges per block (exact)
#define DBW 256                       // dst-bucket width; bucket = d>>8
#define DNB 196                       // 50176/256 dst buckets
// ---- src-side binning for odeg (order-independent histogram, proven R7) ----
#define SBW 512                       // src bin width; bin = s>>9
#define SNB 98                        // ceil(50176/512)
#define BCAP 10240                    // per-src-bin capacity (mean 8163, +23 sigma)

typedef __attribute__((ext_vector_type(4))) float f32x4;
typedef __attribute__((ext_vector_type(8))) short s16x8;

__device__ inline unsigned short f32_to_bf16_rtne(float f) {
    union { float f; unsigned u; } c; c.f = f;
    unsigned u = c.u;
    u += 0x7FFF + ((u >> 16) & 1);
    return (unsigned short)(u >> 16);
}
__device__ inline float bf16_to_f32(unsigned short h) {
    union { unsigned u; float f; } c; c.u = ((unsigned)h) << 16;
    return c.f;
}
__device__ inline unsigned pack_bf2(float a, float b) {
    return (unsigned)f32_to_bf16_rtne(a) | ((unsigned)f32_to_bf16_rtne(b) << 16);
}
__device__ inline void unpack_bf2(unsigned u, float& a, float& b) {
    union { unsigned u; float f; } c0, c1;
    c0.u = u << 16; c1.u = u & 0xFFFF0000u;
    a = c0.f; b = c1.f;
}
__device__ inline void acc_uint4(uint4 v, float* a) {
    float f0, f1;
    unpack_bf2(v.x, f0, f1); a[0] += f0; a[1] += f1;
    unpack_bf2(v.y, f0, f1); a[2] += f0; a[3] += f1;
    unpack_bf2(v.z, f0, f1); a[4] += f0; a[5] += f1;
    unpack_bf2(v.w, f0, f1); a[6] += f0; a[7] += f1;
}

// ---------------- K1: per-block dst-bucket counts | src binning | W-pack ----------------
// R0-R9 scattered-op model: ~40ns/op for scattered sub-line global ops; the old fill's
// 1.6M ops = ~52-57us. This build replaces them with counting sort whose final slot
// order = GLOBAL EDGE-INDEX order, made fully deterministic by K4's per-node sort on
// unique edge-id keys -> replays are bit-identical (fixes R4's replay-divergence mode).

__global__ __launch_bounds__(256) void build_count(const int* __restrict__ src,
                                                   const int* __restrict__ dst,
                                                   int* __restrict__ cnt,     // [ABLK][DNB]
                                                   int* __restrict__ gcurS,
                                                   unsigned short* __restrict__ sbin,
                                                   const float* __restrict__ W0,
                                                   const float* __restrict__ W1,
                                                   const float* __restrict__ W2,
                                                   s16x8* __restrict__ wpk) {
    int b = blockIdx.x;
    if (b < ABLK) {
        __shared__ int cntD[DNB];
        __shared__ int cntS[SNB], baseS[SNB], c2S[SNB];
        for (int i = threadIdx.x; i < DNB; i += 256) cntD[i] = 0;
        for (int i = threadIdx.x; i < SNB; i += 256) { cntS[i] = 0; c2S[i] = 0; }
        __syncthreads();
        int e0 = b * AEDGES;
        for (int i = threadIdx.x; i < AEDGES; i += 256) {
            int s = src[e0 + i], d = dst[e0 + i];
            atomicAdd(&cntD[d >> 8], 1);
            atomicAdd(&cntS[s >> 9], 1);
        }
        __syncthreads();
        for (int i = threadIdx.x; i < DNB; i += 256) cnt[b * DNB + i] = cntD[i];
        for (int i = threadIdx.x; i < SNB; i += 256) baseS[i] = atomicAdd(&gcurS[i], cntS[i]);
        __syncthreads();
        for (int i = threadIdx.x; i < AEDGES; i += 256) {
            int s = src[e0 + i];
            int bs = s >> 9;
            int rs = atomicAdd(&c2S[bs], 1);
            int os = baseS[bs] + rs;
            if (os < BCAP) sbin[bs * BCAP + os] = (unsigned short)s;
        }
    } else {
        // ---- W-pack role ----
        int wid = (b - ABLK) * 4 + (threadIdx.x >> 6);   // 0..95 = layer(3) x ct(8) x ks(4)
        if (wid >= 96) return;
        int lane = threadIdx.x & 63;
        int layer = wid / 32, rem = wid % 32;
        int ct = rem >> 2, ks = rem & 3;
        const float* W = (layer == 0) ? W0 : (layer == 1) ? W1 : W2;
        int col = ct * 16 + (lane & 15);
        int k0  = ks * 32 + (lane >> 4) * 8;
        s16x8 hi, lo;
#pragma unroll
        for (int j = 0; j < 8; j++) {
            float w = W[(k0 + j) * D + col];
            unsigned short h = f32_to_bf16_rtne(w);
            hi[j] = (short)h;
            lo[j] = (short)f32_to_bf16_rtne(w - bf16_to_f32(h));
        }
        int idx = layer * 4096 + (ct * 4 + ks) * 64 + lane;
        wpk[idx]        = hi;
        wpk[idx + 2048] = lo;
    }
}

// ---------------- K2: deterministic scans (in-place cnt -> per-block base) ----------------

__global__ __launch_bounds__(256) void scan_k(int* __restrict__ cnt,      // in-place -> base
                                              int* __restrict__ bstart,   // [DNB]
                                              int* __restrict__ btot) {   // [DNB]
    int k = threadIdx.x;
    if (k < DNB) {
        int run = 0;
#pragma unroll 8
        for (int b = 0; b < ABLK; b++) {       // coalesced: threads read cnt[b*DNB+k]
            int v = cnt[b * DNB + k];
            cnt[b * DNB + k] = run;
            run += v;
        }
        btot[k] = run;
    }
    __syncthreads();
    if (threadIdx.x == 0) {
        int run = 0;
        for (int j = 0; j < DNB; j++) { bstart[j] = run; run += btot[j]; }
    }
}

// ---------------- K3: place edges into bucket-ordered u64 array ----------------
// Entry = (edge_id<<32) | (d&255)<<16 | src. Intra-run order races (LDS atomic) are
// REPAIRED by K4's key sort -> final order deterministic regardless.

__global__ __launch_bounds__(256) void place_k(const int* __restrict__ src,
                                               const int* __restrict__ dst,
                                               const int* __restrict__ base,    // [ABLK][DNB]
                                               const int* __restrict__ bstart,
                                               unsigned long long* __restrict__ dbin) {
    __shared__ int c2[DNB];
    __shared__ int off[DNB];
    int b = blockIdx.x;
    for (int i = threadIdx.x; i < DNB; i += 256) {
        c2[i] = 0;
        off[i] = bstart[i] + base[b * DNB + i];
    }
    __syncthreads();
    int e0 = b * AEDGES;
    for (int i = threadIdx.x; i < AEDGES; i += 256) {
        int e = e0 + i;
        int s = src[e], d = dst[e];
        int bd = d >> 8;
        int idx = atomicAdd(&c2[bd], 1);
        dbin[(size_t)(off[bd] + idx)] =
            ((unsigned long long)(unsigned)e << 32) | ((unsigned)(d & 255) << 16) | (unsigned)s;
    }
}

// ---------------- K4: per-bucket slot fill + per-node edge-id sort (b<DNB) | odeg hist ----------------

__global__ __launch_bounds__(256) void fill_sort(const unsigned long long* __restrict__ dbin,
                                                 const int* __restrict__ bstart,
                                                 const int* __restrict__ btot,
                                                 unsigned short* __restrict__ slots,  // padded NPADN rows
                                                 int* __restrict__ cursor,            // padded NPADN
                                                 const unsigned short* __restrict__ sbin,
                                                 const int* __restrict__ gcurS,
                                                 int* __restrict__ odeg) {
    __shared__ unsigned key[256 * 49];        // stride 49 (pad) to soften sort bank aliasing
    __shared__ unsigned short sv[256 * CAP];
    __shared__ int cur[256];
    __shared__ int scnt[SBW];
    int b = blockIdx.x;
    if (b < DNB) {
        int t = threadIdx.x;
        cur[t] = 0;
        __syncthreads();
        int s0 = bstart[b], n = btot[b];
        for (int i = t; i < n; i += 256) {
            unsigned long long w = dbin[s0 + i];
            int dl = (int)((w >> 16) & 255);
            int p = atomicAdd(&cur[dl], 1);
            if (p < CAP) {
                key[dl * 49 + p] = (unsigned)(w >> 32);
                sv[dl * CAP + p] = (unsigned short)(w & 0xFFFFu);
            }
        }
        __syncthreads();
        // per-node insertion sort by edge id (unique keys; input near-sorted: block-major)
        {
            int m = min(cur[t], CAP);
            int bk = t * 49, bs = t * CAP;
            for (int i = 1; i < m; i++) {
                unsigned ki = key[bk + i];
                unsigned short si = sv[bs + i];
                int j = i - 1;
                while (j >= 0 && key[bk + j] > ki) {
                    key[bk + j + 1] = key[bk + j];
                    sv[bs + j + 1] = sv[bs + j];
                    j--;
                }
                key[bk + j + 1] = ki;
                sv[bs + j + 1] = si;
            }
        }
        __syncthreads();
        int n0 = b * DBW;
        unsigned* dw = (unsigned*)(slots + (size_t)n0 * CAP);
        const unsigned* sw = (const unsigned*)sv;
        for (int i = t; i < DBW * CAP / 2; i += 256) dw[i] = sw[i];
        cursor[n0 + t] = cur[t];
    } else {
        // ---- odeg histogram role (order-independent, proven R7) ----
        int bb = b - DNB;                     // 0..97
        for (int i = threadIdx.x; i < SBW; i += 256) scnt[i] = 0;
        __syncthreads();
        int nE = min(gcurS[bb], BCAP);
        const unsigned short* es = sbin + (size_t)bb * BCAP;
        for (int i = threadIdx.x; i < nE; i += 256)
            atomicAdd(&scnt[es[i] & (SBW - 1)], 1);
        __syncthreads();
        int n0 = bb * SBW;
        for (int i = threadIdx.x; i < SBW; i += 256)
            if (n0 + i < N_NODES) odeg[n0 + i] = scnt[i];
    }
}

// ---------------- h -> bf16 rows pre-scaled by s_out (computed in-kernel from odeg) ----------------

__global__ __launch_bounds__(256) void hconv(const float4* __restrict__ h,
                                             const int* __restrict__ odeg,
                                             float* __restrict__ s_out,
                                             uint2* __restrict__ hbA,
                                             uint2* __restrict__ hbB) {
    int gid = blockIdx.x * 256 + threadIdx.x;   // one float4 (4 channels) per thread
    const int total = N_NODES * 32;
    if (gid < total) {
        int node = gid >> 5;
        float so = rsqrtf(fmaxf((float)odeg[node], 1.0f));
        if ((gid & 31) == 0) s_out[node] = so;   // persist for fused_layer epilogue
        float4 v = h[gid];
        hbA[gid] = make_uint2(pack_bf2(so * v.x, so * v.y), pack_bf2(so * v.z, so * v.w));
    } else if (gid < total + 32) {
        hbA[total + (gid - total)] = make_uint2(0u, 0u);        // zero row of actA
    } else if (gid < total + 64) {
        hbB[total + (gid - total - 32)] = make_uint2(0u, 0u);   // zero row of actB
    }
}

// ---------------- fused layer: gather-aggregate -> LDS(split-bf16) -> MFMA GEMM (R7 form) ----------------

__global__ __launch_bounds__(256) void fused_layer(const uint4* __restrict__ x,
                                                   const unsigned short* __restrict__ slots,
                                                   const int* __restrict__ deg,
                                                   const s16x8* __restrict__ wpk,
                                                   const float* __restrict__ bias,
                                                   const float* __restrict__ s_out,
                                                   float* __restrict__ outf,
                                                   unsigned short* __restrict__ outb) {
    __shared__ s16x8 mHI[16 * 17];
    __shared__ s16x8 mLO[16 * 17];
    int tid = threadIdx.x;
    int row0 = blockIdx.x * 16;

    // ---- phase 1: aggregate ----
    {
        int nloc = tid >> 4;          // local node 0..15
        int l    = tid & 15;          // chunk: channels l*8 .. l*8+7
        int node = row0 + nloc;
        int dgraw = deg[node];
        int dg = min(dgraw, CAP);
        int base = node * CAP;
        // prefetch all slot indices; OOB -> zero row
        int idx0 = (l      < dg) ? (int)slots[base + l]      : N_NODES;
        int idx1 = (16 + l < dg) ? (int)slots[base + 16 + l] : N_NODES;
        int idx2 = (32 + l < dg) ? (int)slots[base + 32 + l] : N_NODES;

        float a[8];
#pragma unroll
        for (int j = 0; j < 8; j++) a[j] = 0.f;

        int nr = (dg + 7) >> 3;       // rounds of 8 (0..6), no tails
        for (int r = 0; r < nr; r++) {
            int c = r >> 1;
            int v = (c == 0) ? idx0 : ((c == 1) ? idx1 : idx2);
            int k = (r & 1) * 8;
            int s0 = __shfl(v, k + 0, 16), s1 = __shfl(v, k + 1, 16);
            int s2 = __shfl(v, k + 2, 16), s3 = __shfl(v, k + 3, 16);
            int s4 = __shfl(v, k + 4, 16), s5 = __shfl(v, k + 5, 16);
            int s6 = __shfl(v, k + 6, 16), s7 = __shfl(v, k + 7, 16);
            uint4 g0 = x[s0 * 16 + l];
            uint4 g1 = x[s1 * 16 + l];
            uint4 g2 = x[s2 * 16 + l];
            uint4 g3 = x[s3 * 16 + l];
            uint4 g4 = x[s4 * 16 + l];
            uint4 g5 = x[s5 * 16 + l];
            uint4 g6 = x[s6 * 16 + l];
            uint4 g7 = x[s7 * 16 + l];
            acc_uint4(g0, a); acc_uint4(g1, a); acc_uint4(g2, a); acc_uint4(g3, a);
            acc_uint4(g4, a); acc_uint4(g5, a); acc_uint4(g6, a); acc_uint4(g7, a);
        }
        float si = rsqrtf(fmaxf((float)dgraw, 1.0f));
        s16x8 ahi, alo;
#pragma unroll
        for (int j = 0; j < 8; j++) {
            float av = a[j] * si;
            unsigned short hh = f32_to_bf16_rtne(av);
            ahi[j] = (short)hh;
            alo[j] = (short)f32_to_bf16_rtne(av - bf16_to_f32(hh));
        }
        mHI[nloc * 17 + l] = ahi;
        mLO[nloc * 17 + l] = alo;
    }
    __syncthreads();

    // ---- phase 2: GEMM ----
    int wv = tid >> 6;                 // wave 0..3 -> col-tiles {2wv, 2wv+1}
    int lane = tid & 63;
    int arow = lane & 15, aq = lane >> 4;
    int ct0 = wv * 2, ct1 = ct0 + 1;
    f32x4 acc0 = (f32x4)0.f, acc1 = (f32x4)0.f;

#pragma unroll
    for (int ks = 0; ks < 4; ks++) {
        s16x8 ahi = mHI[arow * 17 + ks * 4 + aq];
        s16x8 alo = mLO[arow * 17 + ks * 4 + aq];
        int idx0 = (ct0 * 4 + ks) * 64 + lane;
        int idx1 = (ct1 * 4 + ks) * 64 + lane;
        s16x8 b0h = wpk[idx0], b0l = wpk[idx0 + 2048];
        s16x8 b1h = wpk[idx1], b1l = wpk[idx1 + 2048];
        acc0 = __builtin_amdgcn_mfma_f32_16x16x32_bf16(ahi, b0h, acc0, 0, 0, 0);
        acc0 = __builtin_amdgcn_mfma_f32_16x16x32_bf16(alo, b0h, acc0, 0, 0, 0);
        acc0 = __builtin_amdgcn_mfma_f32_16x16x32_bf16(ahi, b0l, acc0, 0, 0, 0);
        acc1 = __builtin_amdgcn_mfma_f32_16x16x32_bf16(ahi, b1h, acc1, 0, 0, 0);
        acc1 = __builtin_amdgcn_mfma_f32_16x16x32_bf16(alo, b1h, acc1, 0, 0, 0);
        acc1 = __builtin_amdgcn_mfma_f32_16x16x32_bf16(ahi, b1l, acc1, 0, 0, 0);
    }

    // C/D: col = lane&15, row = (lane>>4)*4 + reg
    int crow0 = aq * 4;
    float so4[4];
    if (outb) {
#pragma unroll
        for (int r = 0; r < 4; r++) so4[r] = s_out[row0 + crow0 + r];
    }
    int colA = ct0 * 16 + arow, colB = ct1 * 16 + arow;
    float bA = bias[colA], bB = bias[colB];
#pragma unroll
    for (int r = 0; r < 4; r++) {
        size_t rowoff = (size_t)(row0 + crow0 + r) * D;
        float vA = fmaxf(acc0[r] + bA, 0.f);
        float vB = fmaxf(acc1[r] + bB, 0.f);
        if (outf) { outf[rowoff + colA] = vA; outf[rowoff + colB] = vB; }
        if (outb) {
            outb[rowoff + colA] = f32_to_bf16_rtne(so4[r] * vA);
            outb[rowoff + colB] = f32_to_bf16_rtne(so4[r] * vB);
        }
    }
}

// ---------------- launch ----------------

extern "C" void kernel_launch(void* const* d_in, const int* in_sizes, int n_in,
                              void* d_out, int out_size, void* d_ws, size_t ws_size,
                              hipStream_t stream) {
    const float* h  = (const float*)d_in[0];
    const int*  src = (const int*)d_in[1];
    const int*  dst = (const int*)d_in[2];
    const float* W0 = (const float*)d_in[3];
    const float* b0 = (const float*)d_in[4];
    const float* W1 = (const float*)d_in[5];
    const float* b1 = (const float*)d_in[6];
    const float* W2 = (const float*)d_in[7];
    const float* b2 = (const float*)d_in[8];
    float* out = (float*)d_out;

    char* w = (char*)d_ws;
    auto carve = [&](size_t bytes) -> void* {
        void* p = (void*)w;
        w += (bytes + 255) & ~(size_t)255;
        return p;
    };
    int*      gcurS   = (int*)carve(128 * sizeof(int));
    int*      cnt     = (int*)carve((size_t)ABLK * DNB * sizeof(int));     // 313.6 KB
    int*      bstart  = (int*)carve(DNB * sizeof(int));
    int*      btot    = (int*)carve(DNB * sizeof(int));
    int*      cursor  = (int*)carve(NPADN * sizeof(int));                  // in-degree (padded)
    int*      odeg    = (int*)carve(N_NODES * sizeof(int));
    float*    s_out   = (float*)carve(N_NODES * sizeof(float));
    unsigned long long* dbin = (unsigned long long*)carve((size_t)N_EDGES * 8);      // 6.4 MB
    unsigned short* slots = (unsigned short*)carve((size_t)NPADN * CAP * sizeof(unsigned short)); // 4.8 MB
    unsigned short* sbin  = (unsigned short*)carve((size_t)SNB * BCAP * sizeof(unsigned short));  // 2.0 MB
    unsigned short* actA  = (unsigned short*)carve((size_t)(N_NODES + 1) * D * 2);  // 12.8 MB (+zero row)
    unsigned short* actB  = (unsigned short*)carve((size_t)(N_NODES + 1) * D * 2);  // 12.8 MB
    s16x8*    wpk     = (s16x8*)carve(3 * 4096 * sizeof(s16x8));                    // 192 KB

    hipMemsetAsync(gcurS, 0, 128 * sizeof(int), stream);
    build_count<<<ABLK + PACKB, 256, 0, stream>>>(src, dst, cnt, gcurS, sbin,
                                                  W0, W1, W2, wpk);
    scan_k<<<1, 256, 0, stream>>>(cnt, bstart, btot);
    place_k<<<ABLK, 256, 0, stream>>>(src, dst, cnt, bstart, dbin);
    fill_sort<<<DNB + SNB, 256, 0, stream>>>(dbin, bstart, btot, slots, cursor,
                                             sbin, gcurS, odeg);
    hconv<<<(N_NODES * 32 + 64 + 255) / 256, 256, 0, stream>>>((const float4*)h, odeg, s_out,
                                                               (uint2*)actA, (uint2*)actB);

    const int GRID = N_NODES / 16;   // 3125 exact

    // layer 1: actA(bf16, s_out-scaled h) -> actB
    fused_layer<<<GRID, 256, 0, stream>>>((const uint4*)actA, slots, cursor,
                                          wpk, b0, s_out, nullptr, actB);
    // layer 2: actB -> actA
    fused_layer<<<GRID, 256, 0, stream>>>((const uint4*)actB, slots, cursor,
                                          wpk + 4096, b1, s_out, nullptr, actA);
    // layer 3: actA -> d_out (fp32)
    fused_layer<<<GRID, 256, 0, stream>>>((const uint4*)actA, slots, cursor,
                                          wpk + 8192, b2, s_out, out, nullptr);
}